// Round 7
// baseline (150.123 us; speedup 1.0000x reference)
//
#include <hip/hip_runtime.h>
#include <hip/hip_fp16.h>

#define HH 128
#define WW 128
#define CC 64
#define OO 64
#define HWSZ (HH*WW)

typedef _Float16 f16x8 __attribute__((ext_vector_type(8)));
typedef float    f32x4 __attribute__((ext_vector_type(4)));

__device__ __forceinline__ unsigned short f2h(float f) {
    return __half_as_ushort(__float2half_rn(f));
}

// ---------------------------------------------------------------------------
// K0: x NCHW fp32 -> NHWC fp16 (LDS-tiled transpose, +1 pad)
// ---------------------------------------------------------------------------
__global__ __launch_bounds__(256) void transpose_x(const float* __restrict__ x,
                                                   unsigned short* __restrict__ xh) {
    __shared__ float tile[64 * 65];
    int w0 = blockIdx.x * 64, h = blockIdx.y, b = blockIdx.z;
    int t = threadIdx.x;
    const float* xb = x + ((long)b * CC * HWSZ) + h * WW + w0;
#pragma unroll
    for (int i = 0; i < 16; ++i) {
        int idx = i * 256 + t; int c = idx >> 6, w = idx & 63;
        tile[c * 65 + w] = xb[c * HWSZ + w];
    }
    __syncthreads();
    unsigned short* xo = xh + ((long)((b * HH + h) * WW + w0)) * CC;
#pragma unroll
    for (int i = 0; i < 8; ++i) {
        int idx = i * 256 + t; int w = idx >> 5, c = (idx & 31) * 2;
        ushort2 u;
        u.x = f2h(tile[c * 65 + w]);
        u.y = f2h(tile[(c + 1) * 65 + w]);
        *(ushort2*)(xo + w * CC + c) = u;
    }
}

// ---------------------------------------------------------------------------
// K1: weight repack -> fp16.  wdt[k][o][c], wot[k][oc(pad32)][c]
// ---------------------------------------------------------------------------
__global__ __launch_bounds__(256) void prep_w(const float* __restrict__ wd,
                                              const float* __restrict__ wo,
                                              unsigned short* __restrict__ wdt,
                                              unsigned short* __restrict__ wot) {
    int i = blockIdx.x * 256 + threadIdx.x;
    if (i < 9 * 64 * 64) {
        int k = i >> 12, r = i & 4095, o = r >> 6, c = r & 63;
        wdt[i] = f2h(wd[(o * 64 + c) * 9 + k]);
    }
    int j = i - 9 * 64 * 64;
    if (j >= 0 && j < 9 * 32 * 64) {
        int k = j >> 11, r = j & 2047, oc = r >> 6, c = r & 63;
        wot[j] = f2h(oc < 18 ? wo[(oc * 64 + c) * 9 + k] : 0.0f);
    }
}

// ---------------------------------------------------------------------------
// K2: offset conv. Block = (b,h,64px). Stage rows h-1..h+1 into LDS once,
// one barrier, then 9 k-iters of pure ds_read + f16 MFMA.
// ---------------------------------------------------------------------------
__global__ __launch_bounds__(256) void offset_tile(const unsigned short* __restrict__ xh,
                                                   const unsigned short* __restrict__ wot,
                                                   const float* __restrict__ b_off,
                                                   float* __restrict__ ofb) {
    __shared__ unsigned short xr[3 * 68 * 72];   // [row][px(66,pad68)][ch(64,pad72)]
    int w0 = blockIdx.x * 64, h = blockIdx.y, b = blockIdx.z;
    int t = threadIdx.x;

#pragma unroll
    for (int i = 0; i < 7; ++i) {
        int idx = i * 256 + t;
        if (idx < 1584) {
            int r = idx / 528;
            int rem = idx - r * 528;
            int p = rem >> 3, cc = rem & 7;
            int y = h + r - 1, wx = w0 - 1 + p;
            uint4 v = make_uint4(0u, 0u, 0u, 0u);
            if (((unsigned)y < HH) && ((unsigned)wx < WW))
                v = *(const uint4*)(xh + ((long)((b * HH + y) * WW + wx)) * CC + cc * 8);
            *(uint4*)&xr[(r * 68 + p) * 72 + cc * 8] = v;
        }
    }
    __syncthreads();

    int l = t & 63, wv = t >> 6;
    int m = l & 15, q = l >> 4;
    int px0 = wv * 16;
    f32x4 acc0 = {0.f, 0.f, 0.f, 0.f}, acc1 = {0.f, 0.f, 0.f, 0.f};

#pragma unroll
    for (int k = 0; k < 9; ++k) {
        int ky = k / 3, kx = k - ky * 3;
        const unsigned short* ar = &xr[(ky * 68 + px0 + m + kx) * 72 + q * 8];
        f16x8 a0 = *(const f16x8*)(ar);
        f16x8 a1 = *(const f16x8*)(ar + 32);
        const unsigned short* bp = wot + k * 2048 + q * 8;
        f16x8 b00 = *(const f16x8*)(bp + m * 64);
        f16x8 b01 = *(const f16x8*)(bp + m * 64 + 32);
        f16x8 b10 = *(const f16x8*)(bp + (16 + m) * 64);
        f16x8 b11 = *(const f16x8*)(bp + (16 + m) * 64 + 32);
        acc0 = __builtin_amdgcn_mfma_f32_16x16x32_f16(a0, b00, acc0, 0, 0, 0);
        acc0 = __builtin_amdgcn_mfma_f32_16x16x32_f16(a1, b01, acc0, 0, 0, 0);
        acc1 = __builtin_amdgcn_mfma_f32_16x16x32_f16(a0, b10, acc1, 0, 0, 0);
        acc1 = __builtin_amdgcn_mfma_f32_16x16x32_f16(a1, b11, acc1, 0, 0, 0);
    }
    float* dst = ofb + ((long)((b * HH + h) * WW + w0 + px0)) * 18;
    float bo0 = b_off[m];
#pragma unroll
    for (int r = 0; r < 4; ++r)
        dst[(q * 4 + r) * 18 + m] = acc0[r] + bo0;
    if (m < 2) {
        float bo1 = b_off[16 + m];
#pragma unroll
        for (int r = 0; r < 4; ++r)
            dst[(q * 4 + r) * 18 + 16 + m] = acc1[r] + bo1;
    }
}

// ---------------------------------------------------------------------------
// K3: deform conv. Block = (b,h,64px) x 64 o. Double-buffered val LDS only
// (18.4 KB); weights direct from L1-hot wdt. Pipeline per k:
//   issue gathers(k+1) -> B-frag loads(k) -> MFMA(k) from LDS
//   -> convert+ds_write(k+1) -> barrier.
// ---------------------------------------------------------------------------
__global__ __launch_bounds__(256, 4) void deform_tile(const unsigned short* __restrict__ xh,
                                                      const float* __restrict__ ofb,
                                                      const unsigned short* __restrict__ wdt,
                                                      const float* __restrict__ b_dcn,
                                                      float* __restrict__ out) {
    __shared__ unsigned short vs[2][64 * 72];

    int w0 = blockIdx.x * 64, h = blockIdx.y, b = blockIdx.z;
    int t = threadIdx.x;
    int l = t & 63, wv = t >> 6;
    int m = l & 15, q = l >> 4;
    int spx = t >> 2, q4 = t & 3;       // sampler role: pixel, 16-ch chunk

    const unsigned short* xb = xh + (long)b * HWSZ * CC;

    // preload all 9 (dy,dx) for this thread's sampling pixel
    float2 o9[9];
    {
        const float* op = ofb + ((long)((b * HH + h) * WW + w0 + spx)) * 18;
#pragma unroll
        for (int k = 0; k < 9; ++k) o9[k] = *(const float2*)(op + 2 * k);
    }

    f32x4 acc[4];
#pragma unroll
    for (int i = 0; i < 4; ++i) acc[i] = f32x4{0.f, 0.f, 0.f, 0.f};

    f16x8 c00a, c00b, c01a, c01b, c10a, c10b, c11a, c11b;
    float cw0, cw1, cw2, cw3;

    auto issue = [&](int k) {
        int ky = k / 3, kx = k - ky * 3;
        float py  = (float)(h + ky - 1) + o9[k].x;
        float pxf = (float)(w0 + spx + kx - 1) + o9[k].y;
        float y0f = floorf(py), x0f = floorf(pxf);
        float wy = py - y0f, wx = pxf - x0f;
        int y0 = (int)y0f, x0 = (int)x0f, y1 = y0 + 1, x1 = x0 + 1;
        bool vy0 = (unsigned)y0 < HH, vy1 = (unsigned)y1 < HH;
        bool vx0 = (unsigned)x0 < WW, vx1 = (unsigned)x1 < WW;
        int y0c = min(max(y0, 0), HH - 1), y1c = min(max(y1, 0), HH - 1);
        int x0c = min(max(x0, 0), WW - 1), x1c = min(max(x1, 0), WW - 1);
        cw0 = (vy0 && vx0) ? (1.f - wy) * (1.f - wx) : 0.f;
        cw1 = (vy0 && vx1) ? (1.f - wy) * wx : 0.f;
        cw2 = (vy1 && vx0) ? wy * (1.f - wx) : 0.f;
        cw3 = (vy1 && vx1) ? wy * wx : 0.f;
        const unsigned short* p00 = xb + (y0c * WW + x0c) * CC + q4 * 16;
        const unsigned short* p01 = xb + (y0c * WW + x1c) * CC + q4 * 16;
        const unsigned short* p10 = xb + (y1c * WW + x0c) * CC + q4 * 16;
        const unsigned short* p11 = xb + (y1c * WW + x1c) * CC + q4 * 16;
        c00a = *(const f16x8*)p00;  c00b = *(const f16x8*)(p00 + 8);
        c01a = *(const f16x8*)p01;  c01b = *(const f16x8*)(p01 + 8);
        c10a = *(const f16x8*)p10;  c10b = *(const f16x8*)(p10 + 8);
        c11a = *(const f16x8*)p11;  c11b = *(const f16x8*)(p11 + 8);
    };
    auto commit = [&](unsigned short* vb) {
        f16x8 a0, a1;
#pragma unroll
        for (int e = 0; e < 8; ++e) {
            float v = cw0 * (float)c00a[e] + cw1 * (float)c01a[e]
                    + cw2 * (float)c10a[e] + cw3 * (float)c11a[e];
            a0[e] = (_Float16)v;
            float u = cw0 * (float)c00b[e] + cw1 * (float)c01b[e]
                    + cw2 * (float)c10b[e] + cw3 * (float)c11b[e];
            a1[e] = (_Float16)u;
        }
        *(f16x8*)&vb[spx * 72 + q4 * 16] = a0;
        *(f16x8*)&vb[spx * 72 + q4 * 16 + 8] = a1;
    };

    issue(0);
    commit(&vs[0][0]);
    __syncthreads();

#pragma unroll
    for (int k = 0; k < 9; ++k) {
        if (k < 8) issue(k + 1);                       // gathers in flight

        const unsigned short* bp = wdt + k * 4096 + q * 8;   // L1-hot
        f16x8 bf0 = *(const f16x8*)(bp + (0 * 16 + m) * 64);
        f16x8 bf1 = *(const f16x8*)(bp + (0 * 16 + m) * 64 + 32);
        f16x8 bf2 = *(const f16x8*)(bp + (1 * 16 + m) * 64);
        f16x8 bf3 = *(const f16x8*)(bp + (1 * 16 + m) * 64 + 32);
        f16x8 bf4 = *(const f16x8*)(bp + (2 * 16 + m) * 64);
        f16x8 bf5 = *(const f16x8*)(bp + (2 * 16 + m) * 64 + 32);
        f16x8 bf6 = *(const f16x8*)(bp + (3 * 16 + m) * 64);
        f16x8 bf7 = *(const f16x8*)(bp + (3 * 16 + m) * 64 + 32);

        const unsigned short* ap = &vs[k & 1][(wv * 16 + m) * 72 + q * 8];
        f16x8 a0 = *(const f16x8*)(ap);
        f16x8 a1 = *(const f16x8*)(ap + 32);

        acc[0] = __builtin_amdgcn_mfma_f32_16x16x32_f16(a0, bf0, acc[0], 0, 0, 0);
        acc[0] = __builtin_amdgcn_mfma_f32_16x16x32_f16(a1, bf1, acc[0], 0, 0, 0);
        acc[1] = __builtin_amdgcn_mfma_f32_16x16x32_f16(a0, bf2, acc[1], 0, 0, 0);
        acc[1] = __builtin_amdgcn_mfma_f32_16x16x32_f16(a1, bf3, acc[1], 0, 0, 0);
        acc[2] = __builtin_amdgcn_mfma_f32_16x16x32_f16(a0, bf4, acc[2], 0, 0, 0);
        acc[2] = __builtin_amdgcn_mfma_f32_16x16x32_f16(a1, bf5, acc[2], 0, 0, 0);
        acc[3] = __builtin_amdgcn_mfma_f32_16x16x32_f16(a0, bf6, acc[3], 0, 0, 0);
        acc[3] = __builtin_amdgcn_mfma_f32_16x16x32_f16(a1, bf7, acc[3], 0, 0, 0);

        if (k < 8) commit(&vs[(k + 1) & 1][0]);        // waits gathers AFTER mfma
        __syncthreads();
    }

    // epilogue: C/D row(px)=q*4+r (wave px-tile wv*16), col(o)=ot*16+m
#pragma unroll
    for (int ot = 0; ot < 4; ++ot) {
        int o = ot * 16 + m;
        float bo = b_dcn[o];
        f32x4 r = acc[ot];
        r[0] += bo; r[1] += bo; r[2] += bo; r[3] += bo;
        float* dst = out + ((long)(b * OO + o)) * HWSZ + h * WW + w0 + wv * 16 + q * 4;
        *(f32x4*)dst = r;
    }
}

// ---------------------------------------------------------------------------
extern "C" void kernel_launch(void* const* d_in, const int* in_sizes, int n_in,
                              void* d_out, int out_size, void* d_ws, size_t ws_size,
                              hipStream_t stream) {
    const float* x     = (const float*)d_in[0];
    const float* w_off = (const float*)d_in[1];
    const float* b_off = (const float*)d_in[2];
    const float* w_dcn = (const float*)d_in[3];
    const float* b_dcn = (const float*)d_in[4];
    float* out = (float*)d_out;

    char* ws = (char*)d_ws;
    unsigned short* xh  = (unsigned short*)ws;               //  8,388,608 B
    float*          ofb = (float*)(ws + 8388608);            //  4,718,592 B
    unsigned short* wdt = (unsigned short*)(ws + 13107200);  //     73,728 B
    unsigned short* wot = (unsigned short*)(ws + 13180928);  //     36,864 B

    hipLaunchKernelGGL(transpose_x, dim3(2, 128, 4), dim3(256), 0, stream, x, xh);
    hipLaunchKernelGGL(prep_w, dim3(216), dim3(256), 0, stream, w_dcn, w_off, wdt, wot);
    hipLaunchKernelGGL(offset_tile, dim3(2, 128, 4), dim3(256), 0, stream,
                       xh, wot, b_off, ofb);
    hipLaunchKernelGGL(deform_tile, dim3(2, 128, 4), dim3(256), 0, stream,
                       xh, ofb, wdt, b_dcn, out);
}

// Round 8
// 114.716 us; speedup vs baseline: 1.3087x; 1.3087x over previous
//
#include <hip/hip_runtime.h>
#include <hip/hip_fp16.h>

#define HH 128
#define WW 128
#define CC 64
#define OO 64
#define HWSZ (HH*WW)

typedef _Float16 f16x8 __attribute__((ext_vector_type(8)));
typedef float    f32x4 __attribute__((ext_vector_type(4)));

__device__ __forceinline__ unsigned short f2h(float f) {
    return __half_as_ushort(__float2half_rn(f));
}

// ---------------------------------------------------------------------------
// K0: x NCHW fp32 -> NHWC fp16 (LDS-tiled transpose, +1 pad)
// ---------------------------------------------------------------------------
__global__ __launch_bounds__(256) void transpose_x(const float* __restrict__ x,
                                                   unsigned short* __restrict__ xh) {
    __shared__ float tile[64 * 65];
    int w0 = blockIdx.x * 64, h = blockIdx.y, b = blockIdx.z;
    int t = threadIdx.x;
    const float* xb = x + ((long)b * CC * HWSZ) + h * WW + w0;
#pragma unroll
    for (int i = 0; i < 16; ++i) {
        int idx = i * 256 + t; int c = idx >> 6, w = idx & 63;
        tile[c * 65 + w] = xb[c * HWSZ + w];
    }
    __syncthreads();
    unsigned short* xo = xh + ((long)((b * HH + h) * WW + w0)) * CC;
#pragma unroll
    for (int i = 0; i < 8; ++i) {
        int idx = i * 256 + t; int w = idx >> 5, c = (idx & 31) * 2;
        ushort2 u;
        u.x = f2h(tile[c * 65 + w]);
        u.y = f2h(tile[(c + 1) * 65 + w]);
        *(ushort2*)(xo + w * CC + c) = u;
    }
}

// ---------------------------------------------------------------------------
// K1: weight repack -> fp16 in MFMA B-fragment-major order.
//   wdtf[kc(18)][nt(4)][lane(64)][j(8)]  : o = nt*16+(l&15), c = (kc&1)*32+((l>>4)&3)*8+j, k = kc>>1
//   wotf[kc(18)][nt(2)][lane(64)][j(8)]  : same, oc>=18 zero-padded
// One wave-load of a frag = contiguous 1KB burst (8 lines, fully coalesced).
// ---------------------------------------------------------------------------
__global__ __launch_bounds__(256) void prep_w(const float* __restrict__ wd,
                                              const float* __restrict__ wo,
                                              unsigned short* __restrict__ wdtf,
                                              unsigned short* __restrict__ wotf) {
    int i = blockIdx.x * 256 + threadIdx.x;
    if (i < 36864) {
        int j = i & 7, l = (i >> 3) & 63, nt = (i >> 9) & 3, kcb = i >> 11;
        int k = kcb >> 1, cb = kcb & 1;
        int o = nt * 16 + (l & 15);
        int c = cb * 32 + ((l >> 4) & 3) * 8 + j;
        wdtf[i] = f2h(wd[(o * 64 + c) * 9 + k]);
    } else if (i < 36864 + 18432) {
        int jdx = i - 36864;
        int j = jdx & 7, l = (jdx >> 3) & 63, nt = (jdx >> 9) & 1, kcb = jdx >> 10;
        int k = kcb >> 1, cb = kcb & 1;
        int oc = nt * 16 + (l & 15);
        int c = cb * 32 + ((l >> 4) & 3) * 8 + j;
        wotf[jdx] = f2h(oc < 18 ? wo[(oc * 64 + c) * 9 + k] : 0.0f);
    }
}

// ---------------------------------------------------------------------------
// K2: offset conv. Block = (b,h,64px). Stage rows h-1..h+1 into LDS once,
// one barrier, then 9 k-iters of ds_read + coalesced frag-major B + MFMA.
// ---------------------------------------------------------------------------
__global__ __launch_bounds__(256) void offset_tile(const unsigned short* __restrict__ xh,
                                                   const unsigned short* __restrict__ wotf,
                                                   const float* __restrict__ b_off,
                                                   float* __restrict__ ofb) {
    __shared__ __attribute__((aligned(16))) unsigned short xr[3 * 68 * 72];
    int w0 = blockIdx.x * 64, h = blockIdx.y, b = blockIdx.z;
    int t = threadIdx.x;

#pragma unroll
    for (int i = 0; i < 7; ++i) {
        int idx = i * 256 + t;
        if (idx < 1584) {
            int r = idx / 528;
            int rem = idx - r * 528;
            int p = rem >> 3, cc = rem & 7;
            int y = h + r - 1, wx = w0 - 1 + p;
            uint4 v = make_uint4(0u, 0u, 0u, 0u);
            if (((unsigned)y < HH) && ((unsigned)wx < WW))
                v = *(const uint4*)(xh + ((long)((b * HH + y) * WW + wx)) * CC + cc * 8);
            *(uint4*)&xr[(r * 68 + p) * 72 + cc * 8] = v;
        }
    }
    __syncthreads();

    int l = t & 63, wv = t >> 6;
    int m = l & 15, q = l >> 4;
    int px0 = wv * 16;
    f32x4 acc0 = {0.f, 0.f, 0.f, 0.f}, acc1 = {0.f, 0.f, 0.f, 0.f};

#pragma unroll
    for (int k = 0; k < 9; ++k) {
        int ky = k / 3, kx = k - ky * 3;
        const unsigned short* ar = &xr[(ky * 68 + px0 + m + kx) * 72 + q * 8];
        f16x8 a0 = *(const f16x8*)(ar);
        f16x8 a1 = *(const f16x8*)(ar + 32);
        // frag-major B: kcb = k*2+cb, nt = 0/1
        const unsigned short* bk = wotf + (k * 2) * 2 * 512 + l * 8;
        f16x8 b00 = *(const f16x8*)(bk);                 // cb0 nt0
        f16x8 b01 = *(const f16x8*)(bk + 512);           // cb0 nt1
        f16x8 b10 = *(const f16x8*)(bk + 1024);          // cb1 nt0
        f16x8 b11 = *(const f16x8*)(bk + 1536);          // cb1 nt1
        acc0 = __builtin_amdgcn_mfma_f32_16x16x32_f16(a0, b00, acc0, 0, 0, 0);
        acc0 = __builtin_amdgcn_mfma_f32_16x16x32_f16(a1, b10, acc0, 0, 0, 0);
        acc1 = __builtin_amdgcn_mfma_f32_16x16x32_f16(a0, b01, acc1, 0, 0, 0);
        acc1 = __builtin_amdgcn_mfma_f32_16x16x32_f16(a1, b11, acc1, 0, 0, 0);
    }
    float* dst = ofb + ((long)((b * HH + h) * WW + w0 + px0)) * 18;
    float bo0 = b_off[m];
#pragma unroll
    for (int r = 0; r < 4; ++r)
        dst[(q * 4 + r) * 18 + m] = acc0[r] + bo0;
    if (m < 2) {
        float bo1 = b_off[16 + m];
#pragma unroll
        for (int r = 0; r < 4; ++r)
            dst[(q * 4 + r) * 18 + 16 + m] = acc1[r] + bo1;
    }
}

// ---------------------------------------------------------------------------
// K3: deform conv. Block = (b,h,64px) as 2 tiles of 32 px; wave = 16-o n-tile.
// B panel (K=576) lives in 72 VGPRs, loaded once (frag-major, coalesced).
// Per tile: sample ALL 9 k into val_s[32][584] (36 independent gathers/thread,
// no barriers) -> 1 barrier -> 18x(2 ds_read_b128 + 2 MFMA), no barriers.
// ---------------------------------------------------------------------------
__global__ __launch_bounds__(256, 2) void deform_gemm(const unsigned short* __restrict__ xh,
                                                      const float* __restrict__ ofb,
                                                      const unsigned short* __restrict__ wdtf,
                                                      const float* __restrict__ b_dcn,
                                                      float* __restrict__ out) {
    __shared__ __attribute__((aligned(16))) unsigned short val_s[32 * 584];

    int w0 = blockIdx.x * 64, h = blockIdx.y, b = blockIdx.z;
    int t = threadIdx.x;
    int l = t & 63, wv = t >> 6;
    int m = l & 15, q = l >> 4;
    int spx = t >> 3, ch8 = t & 7;          // sampler: pixel 0..31, 16B chunk 0..7

    // ---- B panel in registers: 18 frags, coalesced 1KB bursts ----
    f16x8 Breg[18];
#pragma unroll
    for (int kc = 0; kc < 18; ++kc)
        Breg[kc] = *(const f16x8*)(wdtf + (kc * 4 + wv) * 512 + l * 8);

    const unsigned short* xb = xh + (long)b * HWSZ * CC;
    int o = wv * 16 + m;
    float bo = b_dcn[o];
    float* outo = out + ((long)(b * OO + o)) * HWSZ + h * WW;

#pragma unroll
    for (int g = 0; g < 2; ++g) {
        int wg0 = w0 + g * 32;
        // ---- this thread's pixel offsets ----
        const float* op = ofb + ((long)((b * HH + h) * WW + wg0 + spx)) * 18;
        float2 o9[9];
#pragma unroll
        for (int k = 0; k < 9; ++k) o9[k] = *(const float2*)(op + 2 * k);

        // ---- sample all 9 k: independent gathers, no barriers ----
#pragma unroll
        for (int k = 0; k < 9; ++k) {
            int ky = k / 3, kx = k - ky * 3;
            float py  = (float)(h + ky - 1) + o9[k].x;
            float pxf = (float)(wg0 + spx + kx - 1) + o9[k].y;
            float y0f = floorf(py), x0f = floorf(pxf);
            float wy = py - y0f, wx = pxf - x0f;
            int y0 = (int)y0f, x0 = (int)x0f, y1 = y0 + 1, x1 = x0 + 1;
            bool vy0 = (unsigned)y0 < HH, vy1 = (unsigned)y1 < HH;
            bool vx0 = (unsigned)x0 < WW, vx1 = (unsigned)x1 < WW;
            int y0c = min(max(y0, 0), HH - 1), y1c = min(max(y1, 0), HH - 1);
            int x0c = min(max(x0, 0), WW - 1), x1c = min(max(x1, 0), WW - 1);
            float cw0 = (vy0 && vx0) ? (1.f - wy) * (1.f - wx) : 0.f;
            float cw1 = (vy0 && vx1) ? (1.f - wy) * wx : 0.f;
            float cw2 = (vy1 && vx0) ? wy * (1.f - wx) : 0.f;
            float cw3 = (vy1 && vx1) ? wy * wx : 0.f;
            f16x8 s00 = *(const f16x8*)(xb + (y0c * WW + x0c) * CC + ch8 * 8);
            f16x8 s01 = *(const f16x8*)(xb + (y0c * WW + x1c) * CC + ch8 * 8);
            f16x8 s10 = *(const f16x8*)(xb + (y1c * WW + x0c) * CC + ch8 * 8);
            f16x8 s11 = *(const f16x8*)(xb + (y1c * WW + x1c) * CC + ch8 * 8);
            f16x8 a;
#pragma unroll
            for (int e = 0; e < 8; ++e) {
                float v = cw0 * (float)s00[e] + cw1 * (float)s01[e]
                        + cw2 * (float)s10[e] + cw3 * (float)s11[e];
                a[e] = (_Float16)v;
            }
            *(f16x8*)&val_s[spx * 584 + k * 64 + ch8 * 8] = a;
        }
        __syncthreads();

        // ---- GEMM: K=576, no barriers, B in regs ----
        f32x4 acc0 = {0.f, 0.f, 0.f, 0.f}, acc1 = {0.f, 0.f, 0.f, 0.f};
#pragma unroll
        for (int kc = 0; kc < 18; ++kc) {
            f16x8 a0 = *(const f16x8*)&val_s[m * 584 + kc * 32 + q * 8];
            f16x8 a1 = *(const f16x8*)&val_s[(16 + m) * 584 + kc * 32 + q * 8];
            acc0 = __builtin_amdgcn_mfma_f32_16x16x32_f16(a0, Breg[kc], acc0, 0, 0, 0);
            acc1 = __builtin_amdgcn_mfma_f32_16x16x32_f16(a1, Breg[kc], acc1, 0, 0, 0);
        }

        // ---- epilogue: row(px-local)=q*4+r, col(o)=m ----
        f32x4 r0 = acc0, r1 = acc1;
        r0[0] += bo; r0[1] += bo; r0[2] += bo; r0[3] += bo;
        r1[0] += bo; r1[1] += bo; r1[2] += bo; r1[3] += bo;
        *(f32x4*)(outo + wg0 + q * 4) = r0;
        *(f32x4*)(outo + wg0 + 16 + q * 4) = r1;
        __syncthreads();   // val_s reuse fence for next tile
    }
}

// ---------------------------------------------------------------------------
extern "C" void kernel_launch(void* const* d_in, const int* in_sizes, int n_in,
                              void* d_out, int out_size, void* d_ws, size_t ws_size,
                              hipStream_t stream) {
    const float* x     = (const float*)d_in[0];
    const float* w_off = (const float*)d_in[1];
    const float* b_off = (const float*)d_in[2];
    const float* w_dcn = (const float*)d_in[3];
    const float* b_dcn = (const float*)d_in[4];
    float* out = (float*)d_out;

    char* ws = (char*)d_ws;
    unsigned short* xh   = (unsigned short*)ws;               //  8,388,608 B
    float*          ofb  = (float*)(ws + 8388608);            //  4,718,592 B
    unsigned short* wdtf = (unsigned short*)(ws + 13107200);  //     73,728 B
    unsigned short* wotf = (unsigned short*)(ws + 13180928);  //     36,864 B

    hipLaunchKernelGGL(transpose_x, dim3(2, 128, 4), dim3(256), 0, stream, x, xh);
    hipLaunchKernelGGL(prep_w, dim3(216), dim3(256), 0, stream, w_dcn, w_off, wdtf, wotf);
    hipLaunchKernelGGL(offset_tile, dim3(2, 128, 4), dim3(256), 0, stream,
                       xh, wotf, b_off, ofb);
    hipLaunchKernelGGL(deform_gemm, dim3(2, 128, 4), dim3(256), 0, stream,
                       xh, ofb, wdtf, b_dcn, out);
}

// Round 9
// 104.891 us; speedup vs baseline: 1.4312x; 1.0937x over previous
//
#include <hip/hip_runtime.h>
#include <hip/hip_fp16.h>

#define HH 128
#define WW 128
#define CC 64
#define OO 64
#define HWSZ (HH*WW)

typedef _Float16 f16x8 __attribute__((ext_vector_type(8)));
typedef float    f32x4 __attribute__((ext_vector_type(4)));

__device__ __forceinline__ unsigned short f2h(float f) {
    return __half_as_ushort(__float2half_rn(f));
}

// ---------------------------------------------------------------------------
// K0: prep_all. z<4: x NCHW fp32 -> NHWC fp16 (LDS-tiled transpose).
//     z==4: weight repack -> fp16 in MFMA B-fragment-major order:
//       wdtf[kc(18)][nt(4)][lane(64)][j(8)] : o=nt*16+(l&15), c=(kc&1)*32+((l>>4)&3)*8+j, k=kc>>1
//       wotf[kc(18)][nt(2)][lane(64)][j(8)] : same, oc>=18 zero-padded
// ---------------------------------------------------------------------------
__global__ __launch_bounds__(256) void prep_all(const float* __restrict__ x,
                                                const float* __restrict__ wd,
                                                const float* __restrict__ wo,
                                                unsigned short* __restrict__ xh,
                                                unsigned short* __restrict__ wdtf,
                                                unsigned short* __restrict__ wotf) {
    int t = threadIdx.x;
    if (blockIdx.z == 4) {
        int i = (blockIdx.y * 2 + blockIdx.x) * 256 + t;
        if (i < 36864) {
            int j = i & 7, l = (i >> 3) & 63, nt = (i >> 9) & 3, kcb = i >> 11;
            int k = kcb >> 1, cb = kcb & 1;
            int o = nt * 16 + (l & 15);
            int c = cb * 32 + ((l >> 4) & 3) * 8 + j;
            wdtf[i] = f2h(wd[(o * 64 + c) * 9 + k]);
        } else if (i < 36864 + 18432) {
            int jdx = i - 36864;
            int j = jdx & 7, l = (jdx >> 3) & 63, nt = (jdx >> 9) & 1, kcb = jdx >> 10;
            int k = kcb >> 1, cb = kcb & 1;
            int oc = nt * 16 + (l & 15);
            int c = cb * 32 + ((l >> 4) & 3) * 8 + j;
            wotf[jdx] = f2h(oc < 18 ? wo[(oc * 64 + c) * 9 + k] : 0.0f);
        }
        return;
    }
    __shared__ float tile[64 * 65];
    int w0 = blockIdx.x * 64, h = blockIdx.y, b = blockIdx.z;
    const float* xb = x + ((long)b * CC * HWSZ) + h * WW + w0;
#pragma unroll
    for (int i = 0; i < 16; ++i) {
        int idx = i * 256 + t; int c = idx >> 6, w = idx & 63;
        tile[c * 65 + w] = xb[c * HWSZ + w];
    }
    __syncthreads();
    unsigned short* xo = xh + ((long)((b * HH + h) * WW + w0)) * CC;
#pragma unroll
    for (int i = 0; i < 8; ++i) {
        int idx = i * 256 + t; int w = idx >> 5, c = (idx & 31) * 2;
        ushort2 u;
        u.x = f2h(tile[c * 65 + w]);
        u.y = f2h(tile[(c + 1) * 65 + w]);
        *(ushort2*)(xo + w * CC + c) = u;
    }
}

// ---------------------------------------------------------------------------
// K1: fused offset-conv + deform-conv. Block = (b,h,64px).
// Phase A (round-8 offset_tile): stage rows h-1..h+1 -> LDS, 9x MFMA with
//   frag-major wotf, offsets -> LDS offs[64][20].
// Phase B (round-8 deform_gemm): B panel (18 frags) in VGPRs; per 32-px tile:
//   sample all 9 k (independent 16B gathers, packed-fp16 bilinear) ->
//   val_s -> barrier -> 18x(2 ds_read_b128 + 2 MFMA).
// xr and val_s share one LDS union (phase-separated by barriers).
// ---------------------------------------------------------------------------
__global__ __launch_bounds__(256, 2) void fused_dcn(const unsigned short* __restrict__ xh,
                                                    const unsigned short* __restrict__ wotf,
                                                    const float* __restrict__ b_off,
                                                    const unsigned short* __restrict__ wdtf,
                                                    const float* __restrict__ b_dcn,
                                                    float* __restrict__ out) {
    __shared__ __attribute__((aligned(16))) unsigned short shm[32 * 584]; // union
    __shared__ float offs[64 * 20];
    unsigned short* xr    = shm;   // phase A: [row(3)][px(66,pad68)][ch(64,pad72)]
    unsigned short* val_s = shm;   // phase B: [px(32)][K(576,pad584)]

    int w0 = blockIdx.x * 64, h = blockIdx.y, b = blockIdx.z;
    int t = threadIdx.x;
    int l = t & 63, wv = t >> 6;
    int m = l & 15, q = l >> 4;

    // ================= phase A: offset conv =================
#pragma unroll
    for (int i = 0; i < 7; ++i) {
        int idx = i * 256 + t;
        if (idx < 1584) {
            int r = idx / 528;
            int rem = idx - r * 528;
            int p = rem >> 3, cc = rem & 7;
            int y = h + r - 1, wx = w0 - 1 + p;
            uint4 v = make_uint4(0u, 0u, 0u, 0u);
            if (((unsigned)y < HH) && ((unsigned)wx < WW))
                v = *(const uint4*)(xh + ((long)((b * HH + y) * WW + wx)) * CC + cc * 8);
            *(uint4*)&xr[(r * 68 + p) * 72 + cc * 8] = v;
        }
    }
    __syncthreads();
    {
        int px0 = wv * 16;
        f32x4 acc0 = {0.f, 0.f, 0.f, 0.f}, acc1 = {0.f, 0.f, 0.f, 0.f};
#pragma unroll
        for (int k = 0; k < 9; ++k) {
            int ky = k / 3, kx = k - ky * 3;
            const unsigned short* ar = &xr[(ky * 68 + px0 + m + kx) * 72 + q * 8];
            f16x8 a0 = *(const f16x8*)(ar);
            f16x8 a1 = *(const f16x8*)(ar + 32);
            const unsigned short* bk = wotf + (k * 2) * 2 * 512 + l * 8;
            f16x8 b00 = *(const f16x8*)(bk);
            f16x8 b01 = *(const f16x8*)(bk + 512);
            f16x8 b10 = *(const f16x8*)(bk + 1024);
            f16x8 b11 = *(const f16x8*)(bk + 1536);
            acc0 = __builtin_amdgcn_mfma_f32_16x16x32_f16(a0, b00, acc0, 0, 0, 0);
            acc0 = __builtin_amdgcn_mfma_f32_16x16x32_f16(a1, b10, acc0, 0, 0, 0);
            acc1 = __builtin_amdgcn_mfma_f32_16x16x32_f16(a0, b01, acc1, 0, 0, 0);
            acc1 = __builtin_amdgcn_mfma_f32_16x16x32_f16(a1, b11, acc1, 0, 0, 0);
        }
        float bo0 = b_off[m];
#pragma unroll
        for (int r = 0; r < 4; ++r)
            offs[(px0 + q * 4 + r) * 20 + m] = acc0[r] + bo0;
        if (m < 2) {
            float bo1 = b_off[16 + m];
#pragma unroll
            for (int r = 0; r < 4; ++r)
                offs[(px0 + q * 4 + r) * 20 + 16 + m] = acc1[r] + bo1;
        }
    }
    __syncthreads();

    // ================= phase B: deform conv =================
    int spx = t >> 3, ch8 = t & 7;          // sampler: pixel 0..31, 16B chunk

    f16x8 Breg[18];
#pragma unroll
    for (int kc = 0; kc < 18; ++kc)
        Breg[kc] = *(const f16x8*)(wdtf + (kc * 4 + wv) * 512 + l * 8);

    const unsigned short* xb = xh + (long)b * HWSZ * CC;
    int o = wv * 16 + m;
    float bo = b_dcn[o];
    float* outo = out + ((long)(b * OO + o)) * HWSZ + h * WW;

#pragma unroll
    for (int g = 0; g < 2; ++g) {
        int wg0 = w0 + g * 32;
        const float* oprow = &offs[(g * 32 + spx) * 20];

#pragma unroll
        for (int k = 0; k < 9; ++k) {
            int ky = k / 3, kx = k - ky * 3;
            float2 ov = *(const float2*)(oprow + 2 * k);
            float py  = (float)(h + ky - 1) + ov.x;
            float pxf = (float)(wg0 + spx + kx - 1) + ov.y;
            float y0f = floorf(py), x0f = floorf(pxf);
            float wy = py - y0f, wx = pxf - x0f;
            int y0 = (int)y0f, x0 = (int)x0f, y1 = y0 + 1, x1 = x0 + 1;
            bool vy0 = (unsigned)y0 < HH, vy1 = (unsigned)y1 < HH;
            bool vx0 = (unsigned)x0 < WW, vx1 = (unsigned)x1 < WW;
            int y0c = min(max(y0, 0), HH - 1), y1c = min(max(y1, 0), HH - 1);
            int x0c = min(max(x0, 0), WW - 1), x1c = min(max(x1, 0), WW - 1);
            _Float16 h0 = (_Float16)((vy0 && vx0) ? (1.f - wy) * (1.f - wx) : 0.f);
            _Float16 h1 = (_Float16)((vy0 && vx1) ? (1.f - wy) * wx : 0.f);
            _Float16 h2 = (_Float16)((vy1 && vx0) ? wy * (1.f - wx) : 0.f);
            _Float16 h3 = (_Float16)((vy1 && vx1) ? wy * wx : 0.f);
            f16x8 s00 = *(const f16x8*)(xb + (y0c * WW + x0c) * CC + ch8 * 8);
            f16x8 s01 = *(const f16x8*)(xb + (y0c * WW + x1c) * CC + ch8 * 8);
            f16x8 s10 = *(const f16x8*)(xb + (y1c * WW + x0c) * CC + ch8 * 8);
            f16x8 s11 = *(const f16x8*)(xb + (y1c * WW + x1c) * CC + ch8 * 8);
            f16x8 a = s00 * h0 + s01 * h1 + s10 * h2 + s11 * h3;   // v_pk_fma_f16
            *(f16x8*)&val_s[spx * 584 + k * 64 + ch8 * 8] = a;
        }
        __syncthreads();

        f32x4 acc0 = {0.f, 0.f, 0.f, 0.f}, acc1 = {0.f, 0.f, 0.f, 0.f};
#pragma unroll
        for (int kc = 0; kc < 18; ++kc) {
            f16x8 a0 = *(const f16x8*)&val_s[m * 584 + kc * 32 + q * 8];
            f16x8 a1 = *(const f16x8*)&val_s[(16 + m) * 584 + kc * 32 + q * 8];
            acc0 = __builtin_amdgcn_mfma_f32_16x16x32_f16(a0, Breg[kc], acc0, 0, 0, 0);
            acc1 = __builtin_amdgcn_mfma_f32_16x16x32_f16(a1, Breg[kc], acc1, 0, 0, 0);
        }

        f32x4 r0 = acc0, r1 = acc1;
        r0[0] += bo; r0[1] += bo; r0[2] += bo; r0[3] += bo;
        r1[0] += bo; r1[1] += bo; r1[2] += bo; r1[3] += bo;
        *(f32x4*)(outo + wg0 + q * 4) = r0;
        *(f32x4*)(outo + wg0 + 16 + q * 4) = r1;
        __syncthreads();   // val_s reuse fence
    }
}

// ---------------------------------------------------------------------------
extern "C" void kernel_launch(void* const* d_in, const int* in_sizes, int n_in,
                              void* d_out, int out_size, void* d_ws, size_t ws_size,
                              hipStream_t stream) {
    const float* x     = (const float*)d_in[0];
    const float* w_off = (const float*)d_in[1];
    const float* b_off = (const float*)d_in[2];
    const float* w_dcn = (const float*)d_in[3];
    const float* b_dcn = (const float*)d_in[4];
    float* out = (float*)d_out;

    char* ws = (char*)d_ws;
    unsigned short* xh   = (unsigned short*)ws;              //  8,388,608 B
    unsigned short* wdtf = (unsigned short*)(ws + 8388608);  //     73,728 B
    unsigned short* wotf = (unsigned short*)(ws + 8462336);  //     36,864 B

    hipLaunchKernelGGL(prep_all, dim3(2, 128, 5), dim3(256), 0, stream,
                       x, w_dcn, w_off, xh, wdtf, wotf);
    hipLaunchKernelGGL(fused_dcn, dim3(2, 128, 4), dim3(256), 0, stream,
                       xh, wotf, b_off, wdtf, b_dcn, out);
}